// Round 1
// baseline (2533.326 us; speedup 1.0000x reference)
//
#include <hip/hip_runtime.h>

#define HID 32
#define IN_C 32
#define EDGE_D 16
#define GRAPH_D 16
#define OUT_C 8

// ---------------------------------------------------------------------------
// K0: fold graph embedding into biases.
//   h_G = graph_attr @ W_graph + b_graph                      [16]
//   bias_edge[j] = b_edge_agg[j] + sum_d h_G[d]*W_edge_agg[(80+d)*16+j]
//   bias_node[j] = b_node_agg[j] + sum_d h_G[d]*W_node_agg[(48+d)*32+j]
// ---------------------------------------------------------------------------
__global__ void k_prep(const float* __restrict__ graph_attr,
                       const float* __restrict__ W_graph,
                       const float* __restrict__ b_graph,
                       const float* __restrict__ W_edge_agg,
                       const float* __restrict__ b_edge_agg,
                       const float* __restrict__ W_node_agg,
                       const float* __restrict__ b_node_agg,
                       float* __restrict__ bias_edge,
                       float* __restrict__ bias_node) {
    __shared__ float hG[GRAPH_D];
    int t = threadIdx.x;
    if (t < GRAPH_D) {
        float acc = b_graph[t];
        for (int d = 0; d < GRAPH_D; d++)
            acc += graph_attr[d] * W_graph[d * GRAPH_D + t];
        hG[t] = acc;
    }
    __syncthreads();
    if (t < EDGE_D) {
        float acc = b_edge_agg[t];
        for (int d = 0; d < GRAPH_D; d++)
            acc += hG[d] * W_edge_agg[(2 * HID + EDGE_D + d) * EDGE_D + t];  // rows 80..95
        bias_edge[t] = acc;
    }
    if (t < HID) {
        float acc = b_node_agg[t];
        for (int d = 0; d < GRAPH_D; d++)
            acc += hG[d] * W_node_agg[(HID + EDGE_D + d) * HID + t];        // rows 48..63
        bias_node[t] = acc;
    }
}

// ---------------------------------------------------------------------------
// K1: h_i = x @ W_node + b_node      (thread per node, 32x32)
// ---------------------------------------------------------------------------
__global__ void k_node_emb(const float* __restrict__ x,
                           const float* __restrict__ W,
                           const float* __restrict__ b,
                           float* __restrict__ h, int n) {
    int i = blockIdx.x * blockDim.x + threadIdx.x;
    if (i >= n) return;
    float in[IN_C];
    const float4* xr = (const float4*)(x + (size_t)i * IN_C);
#pragma unroll
    for (int q = 0; q < IN_C / 4; q++) {
        float4 v = xr[q];
        in[4 * q + 0] = v.x; in[4 * q + 1] = v.y;
        in[4 * q + 2] = v.z; in[4 * q + 3] = v.w;
    }
    float acc[HID];
#pragma unroll
    for (int j = 0; j < HID; j++) acc[j] = b[j];
#pragma unroll
    for (int k = 0; k < IN_C; k++) {
        float a = in[k];
#pragma unroll
        for (int j = 0; j < HID; j++) acc[j] += a * W[k * HID + j];
    }
    float4* hr = (float4*)(h + (size_t)i * HID);
#pragma unroll
    for (int q = 0; q < HID / 4; q++) {
        float4 v;
        v.x = acc[4 * q + 0]; v.y = acc[4 * q + 1];
        v.z = acc[4 * q + 2]; v.w = acc[4 * q + 3];
        hr[q] = v;
    }
}

// ---------------------------------------------------------------------------
// K2: per-edge aggregator + scatter-sum into m_sum[row], cnt[row]
//   acc = relu([h_i[row] | h_i[col] | edge_attr] @ W[0:80,:] + bias_edge)
// ---------------------------------------------------------------------------
__global__ void k_edge(const int* __restrict__ ei,
                       const float* __restrict__ h,
                       const float* __restrict__ ea,
                       const float* __restrict__ W,
                       const float* __restrict__ bias,
                       float* __restrict__ msum,
                       float* __restrict__ cnt, int E) {
    int e = blockIdx.x * blockDim.x + threadIdx.x;
    if (e >= E) return;
    int r = ei[e];
    int c = ei[E + e];
    float in[80];
    const float4* hr = (const float4*)(h + (size_t)r * HID);
    const float4* hc = (const float4*)(h + (size_t)c * HID);
    const float4* er = (const float4*)(ea + (size_t)e * EDGE_D);
#pragma unroll
    for (int q = 0; q < 8; q++) {
        float4 v = hr[q];
        in[4 * q + 0] = v.x; in[4 * q + 1] = v.y;
        in[4 * q + 2] = v.z; in[4 * q + 3] = v.w;
    }
#pragma unroll
    for (int q = 0; q < 8; q++) {
        float4 v = hc[q];
        in[32 + 4 * q + 0] = v.x; in[32 + 4 * q + 1] = v.y;
        in[32 + 4 * q + 2] = v.z; in[32 + 4 * q + 3] = v.w;
    }
#pragma unroll
    for (int q = 0; q < 4; q++) {
        float4 v = er[q];
        in[64 + 4 * q + 0] = v.x; in[64 + 4 * q + 1] = v.y;
        in[64 + 4 * q + 2] = v.z; in[64 + 4 * q + 3] = v.w;
    }
    float acc[EDGE_D];
#pragma unroll
    for (int j = 0; j < EDGE_D; j++) acc[j] = bias[j];
#pragma unroll
    for (int k = 0; k < 80; k++) {
        float a = in[k];
#pragma unroll
        for (int j = 0; j < EDGE_D; j++) acc[j] += a * W[k * EDGE_D + j];
    }
    float* dst = msum + (size_t)r * EDGE_D;
#pragma unroll
    for (int j = 0; j < EDGE_D; j++) {
        float v = acc[j] > 0.f ? acc[j] : 0.f;
        atomicAdd(dst + j, v);
    }
    atomicAdd(cnt + r, 1.0f);
}

// ---------------------------------------------------------------------------
// K3: node aggregator + pre-multiplied SAGE-left
//   h_i2 = relu([h_i | m_N] @ W_node_agg[0:48,:] + bias_node)
//   z    = h_i2 @ W_sage_l
// ---------------------------------------------------------------------------
__global__ void k_node2(const float* __restrict__ h,
                        const float* __restrict__ msum,
                        const float* __restrict__ cnt,
                        const float* __restrict__ Wna,
                        const float* __restrict__ bias,
                        const float* __restrict__ Wsl,
                        float* __restrict__ h2out,
                        float* __restrict__ zout, int n) {
    int i = blockIdx.x * blockDim.x + threadIdx.x;
    if (i >= n) return;
    float in[48];
    const float4* hr = (const float4*)(h + (size_t)i * HID);
#pragma unroll
    for (int q = 0; q < 8; q++) {
        float4 v = hr[q];
        in[4 * q + 0] = v.x; in[4 * q + 1] = v.y;
        in[4 * q + 2] = v.z; in[4 * q + 3] = v.w;
    }
    float inv = 1.0f / fmaxf(cnt[i], 1.0f);
    const float4* mr = (const float4*)(msum + (size_t)i * EDGE_D);
#pragma unroll
    for (int q = 0; q < 4; q++) {
        float4 v = mr[q];
        in[32 + 4 * q + 0] = v.x * inv; in[32 + 4 * q + 1] = v.y * inv;
        in[32 + 4 * q + 2] = v.z * inv; in[32 + 4 * q + 3] = v.w * inv;
    }
    float acc[HID];
#pragma unroll
    for (int j = 0; j < HID; j++) acc[j] = bias[j];
#pragma unroll
    for (int k = 0; k < 48; k++) {
        float a = in[k];
#pragma unroll
        for (int j = 0; j < HID; j++) acc[j] += a * Wna[k * HID + j];
    }
#pragma unroll
    for (int j = 0; j < HID; j++) acc[j] = acc[j] > 0.f ? acc[j] : 0.f;
    float4* h2r = (float4*)(h2out + (size_t)i * HID);
#pragma unroll
    for (int q = 0; q < 8; q++) {
        float4 v;
        v.x = acc[4 * q + 0]; v.y = acc[4 * q + 1];
        v.z = acc[4 * q + 2]; v.w = acc[4 * q + 3];
        h2r[q] = v;
    }
    float z[OUT_C];
#pragma unroll
    for (int j = 0; j < OUT_C; j++) z[j] = 0.f;
#pragma unroll
    for (int k = 0; k < HID; k++) {
        float a = acc[k];
#pragma unroll
        for (int j = 0; j < OUT_C; j++) z[j] += a * Wsl[k * OUT_C + j];
    }
    float4* zr = (float4*)(zout + (size_t)i * OUT_C);
    float4 z0, z1;
    z0.x = z[0]; z0.y = z[1]; z0.z = z[2]; z0.w = z[3];
    z1.x = z[4]; z1.y = z[5]; z1.z = z[6]; z1.w = z[7];
    zr[0] = z0; zr[1] = z1;
}

// ---------------------------------------------------------------------------
// K4: scatter z[row] into aggW[col] (mean numerator of SAGE aggregation,
//     already multiplied by W_sage_l since mean and matmul commute)
// ---------------------------------------------------------------------------
__global__ void k_edge2(const int* __restrict__ ei,
                        const float* __restrict__ z,
                        float* __restrict__ aggW,
                        float* __restrict__ cnt2, int E) {
    int e = blockIdx.x * blockDim.x + threadIdx.x;
    if (e >= E) return;
    int r = ei[e];
    int c = ei[E + e];
    const float4* zr = (const float4*)(z + (size_t)r * OUT_C);
    float4 a = zr[0], b = zr[1];
    float* dst = aggW + (size_t)c * OUT_C;
    atomicAdd(dst + 0, a.x); atomicAdd(dst + 1, a.y);
    atomicAdd(dst + 2, a.z); atomicAdd(dst + 3, a.w);
    atomicAdd(dst + 4, b.x); atomicAdd(dst + 5, b.y);
    atomicAdd(dst + 6, b.z); atomicAdd(dst + 7, b.w);
    atomicAdd(cnt2 + c, 1.0f);
}

// ---------------------------------------------------------------------------
// K5: h_nodes = aggW/cnt2 + b_sage_l + h_i2 @ W_sage_r, then mean-pool
//     (wave shuffle reduce, 8 atomics per wave)
// ---------------------------------------------------------------------------
__global__ void k_node3(const float* __restrict__ h2,
                        const float* __restrict__ aggW,
                        const float* __restrict__ cnt2,
                        const int* __restrict__ batch,
                        const float* __restrict__ Wsr,
                        const float* __restrict__ bsl,
                        float* __restrict__ pool,
                        float* __restrict__ ncnt, int n) {
    int i = blockIdx.x * blockDim.x + threadIdx.x;
    float v[OUT_C];
#pragma unroll
    for (int j = 0; j < OUT_C; j++) v[j] = 0.f;
    float cc = 0.f;
    if (i < n && batch[i] == 0) {
        float inv = 1.0f / fmaxf(cnt2[i], 1.0f);
#pragma unroll
        for (int j = 0; j < OUT_C; j++)
            v[j] = aggW[(size_t)i * OUT_C + j] * inv + bsl[j];
        float in[HID];
        const float4* hr = (const float4*)(h2 + (size_t)i * HID);
#pragma unroll
        for (int q = 0; q < 8; q++) {
            float4 w = hr[q];
            in[4 * q + 0] = w.x; in[4 * q + 1] = w.y;
            in[4 * q + 2] = w.z; in[4 * q + 3] = w.w;
        }
#pragma unroll
        for (int k = 0; k < HID; k++) {
            float a = in[k];
#pragma unroll
            for (int j = 0; j < OUT_C; j++) v[j] += a * Wsr[k * OUT_C + j];
        }
        cc = 1.f;
    }
#pragma unroll
    for (int off = 32; off > 0; off >>= 1) {
#pragma unroll
        for (int j = 0; j < OUT_C; j++) v[j] += __shfl_down(v[j], off, 64);
        cc += __shfl_down(cc, off, 64);
    }
    if ((threadIdx.x & 63) == 0) {
#pragma unroll
        for (int j = 0; j < OUT_C; j++) atomicAdd(pool + j, v[j]);
        atomicAdd(ncnt, cc);
    }
}

// ---------------------------------------------------------------------------
// K6: log_softmax of the pooled mean (single thread, 8 values)
// ---------------------------------------------------------------------------
__global__ void k_final(const float* __restrict__ pool,
                        const float* __restrict__ ncnt,
                        float* __restrict__ out) {
    if (threadIdx.x == 0 && blockIdx.x == 0) {
        float c = fmaxf(ncnt[0], 1.0f);
        float p[OUT_C];
        float m = -1e30f;
#pragma unroll
        for (int j = 0; j < OUT_C; j++) {
            p[j] = pool[j] / c;
            m = fmaxf(m, p[j]);
        }
        float s = 0.f;
#pragma unroll
        for (int j = 0; j < OUT_C; j++) s += expf(p[j] - m);
        float l = logf(s);
#pragma unroll
        for (int j = 0; j < OUT_C; j++) out[j] = p[j] - m - l;
    }
}

extern "C" void kernel_launch(void* const* d_in, const int* in_sizes, int n_in,
                              void* d_out, int out_size, void* d_ws, size_t ws_size,
                              hipStream_t stream) {
    const float* x          = (const float*)d_in[0];
    const float* edge_attr  = (const float*)d_in[1];
    const float* graph_attr = (const float*)d_in[2];
    const int*   edge_index = (const int*)d_in[3];
    const int*   batch      = (const int*)d_in[4];
    const float* W_node     = (const float*)d_in[5];
    const float* b_node     = (const float*)d_in[6];
    const float* W_graph    = (const float*)d_in[7];
    const float* b_graph    = (const float*)d_in[8];
    const float* W_edge_agg = (const float*)d_in[9];
    const float* b_edge_agg = (const float*)d_in[10];
    const float* W_node_agg = (const float*)d_in[11];
    const float* b_node_agg = (const float*)d_in[12];
    const float* W_sage_l   = (const float*)d_in[13];
    const float* b_sage_l   = (const float*)d_in[14];
    const float* W_sage_r   = (const float*)d_in[15];

    const int n = in_sizes[0] / IN_C;
    const int E = in_sizes[3] / 2;

    float* ws = (float*)d_ws;
    // workspace layout (floats). Zero-init region first:
    const size_t off_msum = 0;                        // n*16
    const size_t off_cnt  = (size_t)n * 16;           // n
    const size_t off_aggW = (size_t)n * 17;           // n*8
    const size_t off_cnt2 = (size_t)n * 25;           // n
    const size_t off_pool = (size_t)n * 26;           // 8
    const size_t off_ncnt = off_pool + 8;             // 1
    const size_t zero_elems = off_pool + 16;          // pad to 16-float boundary
    // non-zeroed region:
    const size_t off_hi  = zero_elems;                // n*32
    const size_t off_hi2 = off_hi + (size_t)n * HID;  // n*32
    const size_t off_z   = off_hi2 + (size_t)n * HID; // n*8
    const size_t off_be  = off_z + (size_t)n * OUT_C; // 16
    const size_t off_bn  = off_be + 16;               // 32

    hipMemsetAsync(ws, 0, zero_elems * sizeof(float), stream);

    k_prep<<<1, 64, 0, stream>>>(graph_attr, W_graph, b_graph,
                                 W_edge_agg, b_edge_agg, W_node_agg, b_node_agg,
                                 ws + off_be, ws + off_bn);

    k_node_emb<<<(n + 255) / 256, 256, 0, stream>>>(x, W_node, b_node, ws + off_hi, n);

    k_edge<<<(E + 255) / 256, 256, 0, stream>>>(edge_index, ws + off_hi, edge_attr,
                                                W_edge_agg, ws + off_be,
                                                ws + off_msum, ws + off_cnt, E);

    k_node2<<<(n + 255) / 256, 256, 0, stream>>>(ws + off_hi, ws + off_msum, ws + off_cnt,
                                                 W_node_agg, ws + off_bn, W_sage_l,
                                                 ws + off_hi2, ws + off_z, n);

    k_edge2<<<(E + 255) / 256, 256, 0, stream>>>(edge_index, ws + off_z,
                                                 ws + off_aggW, ws + off_cnt2, E);

    k_node3<<<(n + 255) / 256, 256, 0, stream>>>(ws + off_hi2, ws + off_aggW, ws + off_cnt2,
                                                 batch, W_sage_r, b_sage_l,
                                                 ws + off_pool, ws + off_ncnt, n);

    k_final<<<1, 64, 0, stream>>>(ws + off_pool, ws + off_ncnt, (float*)d_out);
}